// Round 7
// baseline (4510.435 us; speedup 1.0000x reference)
//
#include <hip/hip_runtime.h>
#include <hip/hip_bf16.h>
#include <cstddef>

typedef __bf16 bf16_t;
typedef _Float16 f16_t;
typedef bf16_t bf16x8 __attribute__((ext_vector_type(8)));
typedef bf16_t bf16x4 __attribute__((ext_vector_type(4)));
typedef f16_t  f16x8  __attribute__((ext_vector_type(8)));
typedef float  f32x4  __attribute__((ext_vector_type(4)));
typedef unsigned u32x4 __attribute__((ext_vector_type(4)));
typedef unsigned u32x2 __attribute__((ext_vector_type(2)));

#define T_STEPS 256
#define BATCH   32
#define HDIM    1024
#define ZDIM    4096

// ---------------- workspace sizes ----------------
constexpr size_t SZ_HSEQ  = (size_t)8192 * 1024 * 2;      // 16 MiB (hi or lo)
constexpr size_t SZ_HBUF  = (size_t)2 * 32 * 512 * 4;     // 128 KiB tagged fp16-pair h dwords
constexpr size_t SZ_SP    = (size_t)2 * 4 * 8 * 128 * 4;  // 32 KiB tagged LN partials
constexpr size_t SZ_HST   = (size_t)32 * 1024 * 2;        // 64 KiB (hi or lo)
constexpr size_t SZ_CST   = (size_t)32 * 1024 * 4;        // 128 KiB
constexpr size_t SZ_MU    = 256;
constexpr size_t SZ_TAIL  = SZ_HBUF + SZ_SP + 2*SZ_HST + SZ_CST + SZ_MU;
constexpr int    FILL_WORDS = (int)((SZ_HBUF + SZ_SP) / 4);

// ---------------- LDS ----------------
constexpr int SLAB_STRIDE = 264;                 // W staging rows (fp16)
constexpr int HL_STRIDE   = 1040;                // h rows (fp16), 2080 B
// post-staging: hl [8][1040] fp16 @0, swred[4][8][2] @16640, sredS[8][2] after
constexpr int SCAN_LDS    = 2 * 64 * SLAB_STRIDE * 2;  // 67584 (staging dominates)

__global__ void init_fill(unsigned* __restrict__ p, int n) {
    int i = blockIdx.x * blockDim.x + threadIdx.x;
    if (i < n) p[i] = 0xFFFFFFFFu;   // poison: tag never matches t=0/1 polls
}

__device__ __forceinline__ void split_bf16(float v, bf16_t& hi, bf16_t& lo) {
    hi = (bf16_t)v;
    lo = (bf16_t)(v - (float)hi);
}
__device__ __forceinline__ unsigned short f16_bits(f16_t f) {
    union { unsigned short u; f16_t f2; } x; x.f2 = f; return x.u;
}
__device__ __forceinline__ float tanh_fast(float x) {
    float e = __expf(2.f * x);
    return 1.f - 2.f * __builtin_amdgcn_rcpf(e + 1.f);
}
__device__ __forceinline__ void bar_lds() {
    asm volatile("s_waitcnt lgkmcnt(0)" ::: "memory");
    __builtin_amdgcn_s_barrier();
    asm volatile("" ::: "memory");
}

// ---------------- input-projection GEMM: 128x64 tile, bf16x2 3-chain -------------
// Same k-order and per-acc chain order as the 64x64 version -> bit-identical xp.
// 2x M-tile halves B(W)-staging + split-VALU cost per output.
// MODE 0: A fp32 with series row-remap (layer0, K=256)
// MODE 1: A pre-split hi/lo bf16 (layer1, K=1024)
template<int KTOT, int MODE>
__global__ __launch_bounds__(256) void gemm_xp(
    const float*  __restrict__ Afp,
    const bf16_t* __restrict__ Ahi,
    const bf16_t* __restrict__ Alo,
    const float*  __restrict__ W,
    const float*  __restrict__ bias,
    float*        __restrict__ xp,
    int t0)
{
    __shared__ bf16_t Ash[2][64][40], Asl[2][64][40], Bsh[64][40], Bsl[64][40];
    const int bm = blockIdx.x >> 6;        // M/128 tiles
    const int bn = blockIdx.x & 63;        // N/64 tiles
    const int tid  = threadIdx.x;
    const int lane = tid & 63;
    const int w    = tid >> 6;
    const int q    = lane >> 4;
    const int l15  = lane & 15;

    f32x4 acc[2][4] = {};

    const int sm = tid & 63;
    const int sk = (tid >> 6) * 8;
    const int grb = t0*32 + bm*128;
    const float*  Arow0 = nullptr; const float* Arow1 = nullptr;
    const bf16_t *Ah0=nullptr,*Al0=nullptr,*Ah1=nullptr,*Al1=nullptr;
    if constexpr (MODE == 0) {
        int g0 = grb + sm;       int t0_ = g0 >> 5, b0_ = g0 & 31;
        int g1 = grb + 64 + sm;  int t1_ = g1 >> 5, b1_ = g1 & 31;
        Arow0 = Afp + ((size_t)b0_ * T_STEPS + t0_) * 256;
        Arow1 = Afp + ((size_t)b1_ * T_STEPS + t1_) * 256;
    } else {
        Ah0 = Ahi + (size_t)(grb + sm) * HDIM;
        Al0 = Alo + (size_t)(grb + sm) * HDIM;
        Ah1 = Ahi + (size_t)(grb + 64 + sm) * HDIM;
        Al1 = Alo + (size_t)(grb + 64 + sm) * HDIM;
    }
    const int gcol = bn*64 + sm;

    for (int k0 = 0; k0 < KTOT; k0 += 32) {
        if constexpr (MODE == 0) {
            f32x4 a0 = *(const f32x4*)(Arow0 + k0 + sk);
            f32x4 a1 = *(const f32x4*)(Arow0 + k0 + sk + 4);
            f32x4 c0 = *(const f32x4*)(Arow1 + k0 + sk);
            f32x4 c1 = *(const f32x4*)(Arow1 + k0 + sk + 4);
            #pragma unroll
            for (int j = 0; j < 4; ++j) {
                split_bf16(a0[j], Ash[0][sm][sk+j],   Asl[0][sm][sk+j]);
                split_bf16(a1[j], Ash[0][sm][sk+4+j], Asl[0][sm][sk+4+j]);
                split_bf16(c0[j], Ash[1][sm][sk+j],   Asl[1][sm][sk+j]);
                split_bf16(c1[j], Ash[1][sm][sk+4+j], Asl[1][sm][sk+4+j]);
            }
        } else {
            *(bf16x8*)&Ash[0][sm][sk] = *(const bf16x8*)(Ah0 + k0 + sk);
            *(bf16x8*)&Asl[0][sm][sk] = *(const bf16x8*)(Al0 + k0 + sk);
            *(bf16x8*)&Ash[1][sm][sk] = *(const bf16x8*)(Ah1 + k0 + sk);
            *(bf16x8*)&Asl[1][sm][sk] = *(const bf16x8*)(Al1 + k0 + sk);
        }
        #pragma unroll
        for (int j = 0; j < 8; ++j) {
            float wv = W[(size_t)(k0 + sk + j) * ZDIM + gcol];
            split_bf16(wv, Bsh[sm][sk+j], Bsl[sm][sk+j]);
        }
        __syncthreads();
        #pragma unroll
        for (int mt = 0; mt < 2; ++mt) {
            const int half = w >> 1;
            const int rif  = (w & 1)*32 + mt*16 + l15;
            bf16x8 ah = *(const bf16x8*)&Ash[half][rif][q*8];
            bf16x8 al = *(const bf16x8*)&Asl[half][rif][q*8];
            #pragma unroll
            for (int nt = 0; nt < 4; ++nt) {
                bf16x8 bh = *(const bf16x8*)&Bsh[nt*16 + l15][q*8];
                bf16x8 bl = *(const bf16x8*)&Bsl[nt*16 + l15][q*8];
                acc[mt][nt] = __builtin_amdgcn_mfma_f32_16x16x32_bf16(ah, bh, acc[mt][nt], 0, 0, 0);
                acc[mt][nt] = __builtin_amdgcn_mfma_f32_16x16x32_bf16(al, bh, acc[mt][nt], 0, 0, 0);
                acc[mt][nt] = __builtin_amdgcn_mfma_f32_16x16x32_bf16(ah, bl, acc[mt][nt], 0, 0, 0);
            }
        }
        __syncthreads();
    }
    #pragma unroll
    for (int mt = 0; mt < 2; ++mt) {
        int row = bm*128 + w*32 + mt*16 + q*4;
        #pragma unroll
        for (int nt = 0; nt < 4; ++nt) {
            int col = bn*64 + nt*16 + l15;
            float bia = bias[col];
            #pragma unroll
            for (int r = 0; r < 4; ++r)
                xp[(size_t)(row + r)*ZDIM + col] = acc[mt][nt][r] + bia;
        }
    }
}

// ---------------- persistent recurrent scan: r3 shape + pair-issued polls --------
// grid 256 x 256. Protocol identical to r3 (2-hop tag-in-data fp16 h broadcast).
// ONLY change vs r3: both poll loops issue TWO back-to-back loads per retry round
// (both in flight ~4cy apart) and accept whichever validates -> expected retry
// overshoot halves from ~1 MALL-RT to ~0.5. Arithmetic bit-identical to r3.
__global__ __launch_bounds__(256, 1) void scan_kernel(
    const float* __restrict__ Wh,      // [1024][4096] fp32 recurrent rows
    const float* __restrict__ xp,      // [cT*32][4096] fp32 x-proj (incl bias)
    const float* __restrict__ gamma,
    const float* __restrict__ beta,
    unsigned*    Hbuf,                 // [2][32][512] tagged fp16-pair h dwords
    unsigned*    Sp,                   // [2][4][8][128] tagged LN partials
    bf16_t*      __restrict__ hseq_hi, // [T*32][1024] or null (layer0)
    bf16_t*      __restrict__ hseq_lo,
    float*       __restrict__ outlast, // [32][1024] or null (layer1)
    bf16_t*      __restrict__ hst_hi,  // [32][1024] chunk-carry
    bf16_t*      __restrict__ hst_lo,
    float*       __restrict__ cstate,  // [32][1024]
    float*       __restrict__ mustate, // [32]
    int t0, int t1)
{
    extern __shared__ char smem[];
    f16_t* slab_hi = (f16_t*)smem;                        // W staging
    f16_t* slab_lo = (f16_t*)(smem + 64*SLAB_STRIDE*2);
    f16_t* hl      = (f16_t*)smem;                        // [8][1040] fp16 post-staging
    float* swred   = (float*)(smem + 8*HL_STRIDE*2);      // [4 waves][8 batch][2]
    float* sredS   = swred + 64;                          // [8 batch][2]

    const int gid = blockIdx.x >> 6;
    const int lid = blockIdx.x & 63;
    const int B0  = gid * 8;
    const int H0  = lid * 16;
    const int tid  = threadIdx.x;
    const int lane = tid & 63;
    const int w    = tid >> 6;
    const int q    = lane >> 4;
    const int l15  = lane & 15;

    // ---- stage recurrent W slice -> registers (fp16 hi + fp16 lo*2048)
    f16x8 wf_hi[32], wf_lo[32];
    {
        const int kw   = tid >> 6;
        const int strip= (tid >> 4) & 3;
        const int col  = tid & 15;
        const int gc2  = strip*1024 + H0 + col;
        const int rr_w = col*4 + strip;
        #pragma unroll
        for (int s = 0; s < 4; ++s) {
            for (int j = 0; j < 64; ++j) {
                int kk = j*4 + kw;
                float v = Wh[(size_t)(s*256 + kk)*ZDIM + gc2];
                f16_t hi = (f16_t)v;
                f16_t lo = (f16_t)((v - (float)hi) * 2048.f);
                slab_hi[rr_w*SLAB_STRIDE + kk] = hi;
                slab_lo[rr_w*SLAB_STRIDE + kk] = lo;
            }
            __syncthreads();
            #pragma unroll
            for (int kbl = 0; kbl < 8; ++kbl) {
                wf_hi[s*8+kbl] = *(const f16x8*)&slab_hi[(16*w + l15)*SLAB_STRIDE + kbl*32 + q*8];
                wf_lo[s*8+kbl] = *(const f16x8*)&slab_lo[(16*w + l15)*SLAB_STRIDE + kbl*32 + q*8];
            }
            __syncthreads();
        }
    }

    // owner identity (MFMA C map)
    const int  bidx  = l15;
    const bool valid = bidx < 8;
    const int  batch = B0 + bidx;
    const int  hcl   = 4*w + q;
    const int  hcg   = H0 + hcl;
    const size_t xpbase = (size_t)batch * ZDIM + (size_t)H0 + hcl;
    const int hrow  = (l15 < 8) ? l15 : 7;

    // hop2 reader identity: wave w + lane-half owns rows rr = 2w + half
    const int half   = lane >> 5;
    const int lane32 = lane & 31;
    const int rr     = 2*w + half;
    const int rbatch = B0 + rr;

    float g_own = 0.f, b_own = 0.f;
    if (valid) { g_own = gamma[hcg]; b_own = beta[hcg]; }

    float c = 0.f, mu_own = 0.f;
    if (t0 > 0) {
        if (valid) {
            c = cstate[(size_t)batch*HDIM + hcg];
            mu_own = mustate[batch];
        }
        const int cb = tid * 4;
        #pragma unroll
        for (int r = 0; r < 8; ++r) {
            bf16x4 vh = *(const bf16x4*)&hst_hi[(size_t)(B0+r)*HDIM + cb];
            bf16x4 vl = *(const bf16x4*)&hst_lo[(size_t)(B0+r)*HDIM + cb];
            #pragma unroll
            for (int e = 0; e < 4; ++e)
                hl[r*HL_STRIDE + cb + e] = (f16_t)((float)vh[e] + (float)vl[e]);
        }
    }
    __syncthreads();

    // preload xp for first step
    float xpv[4] = {0.f, 0.f, 0.f, 0.f};
    if (valid) {
        const float* xpt = xp + xpbase;
        #pragma unroll
        for (int r = 0; r < 4; ++r) xpv[r] = xpt[(size_t)r * 1024];
    }

    const bool is_l0 = (hseq_hi != nullptr);

    #pragma unroll 1
    for (int t = t0; t < t1; ++t) {
        f32x4 acc_hh = {0.f,0.f,0.f,0.f}, acc_lh = acc_hh;
        if (t > 0) {
            const f16_t* Bp = hl + (size_t)hrow * HL_STRIDE + q*8;
            #pragma unroll
            for (int kb = 0; kb < 32; ++kb) {
                f16x8 b = *(const f16x8*)(Bp + kb*32);
                acc_hh = __builtin_amdgcn_mfma_f32_16x16x32_f16(wf_hi[kb], b, acc_hh, 0, 0, 0);
                acc_lh = __builtin_amdgcn_mfma_f32_16x16x32_f16(wf_lo[kb], b, acc_lh, 0, 0, 0);
            }
        }
        float z[4];
        #pragma unroll
        for (int r = 0; r < 4; ++r)
            z[r] = (acc_hh[r] + acc_lh[r]*(1.f/2048.f)) + xpv[r];

        float zi = fminf(fmaxf(z[0], -6.f), 3.f);
        float zf = fminf(fmaxf(z[1], -6.f), 3.f);
        float ig = __expf(zi);
        float fg = __expf(zf);
        float cand = tanh_fast(z[2]);
        float sg = 1.f / (1.f + __expf(-z[3]));
        c = fg * c + ig * cand;

        const int par = t & 1;
        const unsigned tg = (unsigned)(t & 3);
        const unsigned tgpat = (unsigned)(t & 1) | (((unsigned)(t >> 1) & 1u) << 16);

        // ---- hop1: intra-block LN partials -> tagged publish
        float dm = valid ? (c - mu_own) : 0.f;
        float s1 = dm, s2 = dm*dm;
        s1 += __shfl_xor(s1, 16); s2 += __shfl_xor(s2, 16);
        s1 += __shfl_xor(s1, 32); s2 += __shfl_xor(s2, 32);
        if (lane < 8) { swred[(w*8+lane)*2] = s1; swred[(w*8+lane)*2+1] = s2; }
        bar_lds();   // B1: swred ready

        if (tid < 8) {
            float S1p = swred[tid*2]       + swred[(8+tid)*2]
                      + swred[(16+tid)*2]  + swred[(24+tid)*2];
            float S2p = swred[tid*2+1]     + swred[(8+tid)*2+1]
                      + swred[(16+tid)*2+1]+ swred[(24+tid)*2+1];
            u32x2 pk;
            pk[0] = (__float_as_uint(S1p) & ~3u) | tg;
            pk[1] = (__float_as_uint(S2p) & ~3u) | tg;
            *(volatile u32x2*)(Sp + (((size_t)par*4 + gid)*8 + tid)*128 + (size_t)lid*2) = pk;
        }

        // xp prefetch for t+1: flies through both polls
        if (valid && t+1 < t1) {
            const float* xpt = xp + (size_t)(t+1 - t0) * (BATCH*ZDIM) + xpbase;
            #pragma unroll
            for (int r = 0; r < 4; ++r) xpv[r] = xpt[(size_t)r * 1024];
        }

        // ---- poll partials (pair-issued), 32-lane reduce per batch
        {
            const int prr = tid >> 5, jj = tid & 31;
            volatile const u32x4* spb =
                (volatile const u32x4*)(Sp + (((size_t)par*4 + gid)*8 + prr)*128 + (size_t)jj*4);
            u32x4 sv = *spb;
            while ((((sv[0]^tg)|(sv[1]^tg)|(sv[2]^tg)|(sv[3]^tg)) & 3u) != 0u) {
                u32x4 a = *spb;            // two loads in flight per retry round
                u32x4 b = *spb;
                unsigned ma = ((a[0]^tg)|(a[1]^tg)|(a[2]^tg)|(a[3]^tg)) & 3u;
                sv = ma ? b : a;
                if (!(((sv[0]^tg)|(sv[1]^tg)|(sv[2]^tg)|(sv[3]^tg)) & 3u)) break;
                __builtin_amdgcn_s_sleep(1);
            }
            float s1p = __uint_as_float(sv[0] & ~3u) + __uint_as_float(sv[2] & ~3u);
            float s2p = __uint_as_float(sv[1] & ~3u) + __uint_as_float(sv[3] & ~3u);
            #pragma unroll
            for (int m = 1; m < 32; m <<= 1) {
                s1p += __shfl_xor(s1p, m);
                s2p += __shfl_xor(s2p, m);
            }
            if (jj == 0) { sredS[prr*2] = s1p; sredS[prr*2+1] = s2p; }
        }
        bar_lds();   // B2: sredS ready

        // ---- owner: LN + exact h; publish h~ fp16 pair (tag: 1 LSB per fp16)
        const bool carry = (t == t1-1) && (t1 < T_STEPS);
        unsigned hbs = 0;
        if (valid) {
            float S1 = sredS[bidx*2], S2 = sredS[bidx*2+1];
            float dmu = S1 * (1.f/1024.f);
            float mu  = mu_own + dmu;
            float var = S2 * (1.f/1024.f) - dmu*dmu;
            float rsig = rsqrtf(var + 1e-5f);
            mu_own = mu;
            float ln   = (c - mu) * rsig * g_own + b_own;
            float hval = sg * tanh_fast(ln);
            if (is_l0) {
                bf16_t hi, lo; split_bf16(hval, hi, lo);
                hseq_hi[((size_t)t*32 + batch)*HDIM + hcg] = hi;
                hseq_lo[((size_t)t*32 + batch)*HDIM + hcg] = lo;
            }
            if (carry) {
                bf16_t hi, lo; split_bf16(hval, hi, lo);
                hst_hi[(size_t)batch*HDIM + hcg] = hi;
                hst_lo[(size_t)batch*HDIM + hcg] = lo;
            }
            if (outlast && t == T_STEPS-1)
                outlast[(size_t)batch*HDIM + hcg] = hval;
            unsigned tb = (q & 1) ? ((unsigned)(t >> 1) & 1u) : ((unsigned)t & 1u);
            hbs = ((unsigned)f16_bits((f16_t)hval) & 0xFFFEu) | tb;
        }
        unsigned pb2 = __shfl_xor(hbs, 16);   // partner col's bits (q ^ 1)
        if (valid && !(q & 1)) {
            unsigned dw = hbs | (pb2 << 16);
            *(volatile unsigned*)(Hbuf + ((size_t)par*32 + batch)*512 + ((unsigned)hcg >> 1)) = dw;
        }

        // ---- hop2: poll fp16 h pairs straight into LDS (pair-issued retries)
        if (t + 1 < t1) {
            volatile const u32x4* hb4 =
                (volatile const u32x4*)(Hbuf + ((size_t)par*32 + rbatch)*512) + lane32;
            u32x4 pv[4];
            #pragma unroll
            for (int k = 0; k < 4; ++k) pv[k] = hb4[(size_t)k*32];
            for (;;) {
                bool bad = false;
                #pragma unroll
                for (int k = 0; k < 4; ++k) {
                    unsigned m = ((pv[k][0]^tgpat)|(pv[k][1]^tgpat)
                                 |(pv[k][2]^tgpat)|(pv[k][3]^tgpat)) & 0x00010001u;
                    if (m) {
                        u32x4 a = hb4[(size_t)k*32];   // two in flight
                        u32x4 b = hb4[(size_t)k*32];
                        unsigned ma = ((a[0]^tgpat)|(a[1]^tgpat)
                                      |(a[2]^tgpat)|(a[3]^tgpat)) & 0x00010001u;
                        pv[k] = ma ? b : a;
                        unsigned mk = ((pv[k][0]^tgpat)|(pv[k][1]^tgpat)
                                      |(pv[k][2]^tgpat)|(pv[k][3]^tgpat)) & 0x00010001u;
                        bad |= (mk != 0u);
                    }
                }
                if (!bad) break;
                __builtin_amdgcn_s_sleep(1);
            }
            #pragma unroll
            for (int k = 0; k < 4; ++k) {
                u32x4 vv = pv[k] & 0xFFFEFFFEu;   // clear tag bits -> valid fp16 pairs
                *(u32x4*)&hl[(size_t)rr*HL_STRIDE + (size_t)k*256 + (size_t)lane32*8] = vv;
            }
            bar_lds();   // B3: hl ready for next step's MFMA
        }
    }

    // chunk-carry state (owners hold c and mu for their batch)
    if (t1 < T_STEPS) {
        if (valid) {
            cstate[(size_t)batch*HDIM + hcg] = c;
            if (lid == 0 && hcl == 0) mustate[batch] = mu_own;
        }
    }
}

extern "C" void kernel_launch(void* const* d_in, const int* in_sizes, int n_in,
                              void* d_out, int out_size, void* d_ws, size_t ws_size,
                              hipStream_t stream) {
    (void)in_sizes; (void)n_in;
    const float* series = (const float*)d_in[0];
    const float* W0  = (const float*)d_in[1];
    const float* b0  = (const float*)d_in[2];
    const float* g0  = (const float*)d_in[3];
    const float* be0 = (const float*)d_in[4];
    const float* W1  = (const float*)d_in[5];
    const float* b1  = (const float*)d_in[6];
    const float* g1  = (const float*)d_in[7];
    const float* be1 = (const float*)d_in[8];
    float* out = (float*)d_out;
    unsigned char* ws = (unsigned char*)d_ws;

    int cT = 0;
    const int cands[4] = {256, 128, 64, 32};
    for (int i = 0; i < 4; ++i) {
        size_t need = (size_t)cands[i]*32*ZDIM*4 + 2*SZ_HSEQ + SZ_TAIL;
        if (need <= ws_size) { cT = cands[i]; break; }
    }
    if (cT == 0) {
        (void)hipMemsetAsync(d_out, 0, (size_t)out_size * sizeof(float), stream);
        return;
    }
    const size_t sz_xp = (size_t)cT*32*ZDIM*4;
    unsigned char* p = ws;
    float*    xp      = (float*)p;    p += sz_xp;
    bf16_t*   hseq_hi = (bf16_t*)p;   p += SZ_HSEQ;
    bf16_t*   hseq_lo = (bf16_t*)p;   p += SZ_HSEQ;
    unsigned* Hbuf    = (unsigned*)p; p += SZ_HBUF;   // Hbuf+Sp contiguous for init_fill
    unsigned* Sp      = (unsigned*)p; p += SZ_SP;
    bf16_t*   hst_hi  = (bf16_t*)p;   p += SZ_HST;
    bf16_t*   hst_lo  = (bf16_t*)p;   p += SZ_HST;
    float*    cstate  = (float*)p;    p += SZ_CST;
    float*    mustate = (float*)p;

    (void)hipFuncSetAttribute((const void*)scan_kernel,
                              hipFuncAttributeMaxDynamicSharedMemorySize, SCAN_LDS);

    const int nch = T_STEPS / cT;
    const int gemm_grid = (cT*32/128) * (ZDIM/64);

    // ---- layer 0 ----
    init_fill<<<(FILL_WORDS + 255)/256, 256, 0, stream>>>(Hbuf, FILL_WORDS);
    for (int ci = 0; ci < nch; ++ci) {
        int t0 = ci*cT, t1 = t0 + cT;
        gemm_xp<256, 0><<<gemm_grid, 256, 0, stream>>>(
            series, nullptr, nullptr, W0, b0, xp, t0);
        scan_kernel<<<256, 256, SCAN_LDS, stream>>>(
            W0 + (size_t)256*ZDIM, xp, g0, be0, Hbuf, Sp,
            hseq_hi, hseq_lo, nullptr, hst_hi, hst_lo, cstate, mustate, t0, t1);
    }
    // ---- layer 1 (re-poison kills cross-layer tag aliasing at t=2,3) ----
    init_fill<<<(FILL_WORDS + 255)/256, 256, 0, stream>>>(Hbuf, FILL_WORDS);
    for (int ci = 0; ci < nch; ++ci) {
        int t0 = ci*cT, t1 = t0 + cT;
        gemm_xp<1024, 1><<<gemm_grid, 256, 0, stream>>>(
            nullptr, hseq_hi, hseq_lo, W1, b1, xp, t0);
        scan_kernel<<<256, 256, SCAN_LDS, stream>>>(
            W1 + (size_t)1024*ZDIM, xp, g1, be1, Hbuf, Sp,
            nullptr, nullptr, out, hst_hi, hst_lo, cstate, mustate, t0, t1);
    }
}

// Round 8
// 4169.489 us; speedup vs baseline: 1.0818x; 1.0818x over previous
//
#include <hip/hip_runtime.h>
#include <hip/hip_bf16.h>
#include <cstddef>

typedef __bf16 bf16_t;
typedef _Float16 f16_t;
typedef bf16_t bf16x8 __attribute__((ext_vector_type(8)));
typedef bf16_t bf16x4 __attribute__((ext_vector_type(4)));
typedef f16_t  f16x8  __attribute__((ext_vector_type(8)));
typedef float  f32x4  __attribute__((ext_vector_type(4)));
typedef unsigned u32x4 __attribute__((ext_vector_type(4)));
typedef unsigned u32x2 __attribute__((ext_vector_type(2)));

#define T_STEPS 256
#define BATCH   32
#define HDIM    1024
#define ZDIM    4096

// ---------------- workspace sizes ----------------
constexpr size_t SZ_HSEQ  = (size_t)8192 * 1024 * 2;      // 16 MiB (hi or lo)
constexpr size_t SZ_HBUF  = (size_t)2 * 32 * 512 * 4;     // 128 KiB tagged fp16-pair h dwords
constexpr size_t SZ_SP    = (size_t)2 * 4 * 8 * 128 * 4;  // 32 KiB tagged LN partials
constexpr size_t SZ_HST   = (size_t)32 * 1024 * 2;        // 64 KiB (hi or lo)
constexpr size_t SZ_CST   = (size_t)32 * 1024 * 4;        // 128 KiB
constexpr size_t SZ_MU    = 256;
constexpr size_t SZ_TAIL  = SZ_HBUF + SZ_SP + 2*SZ_HST + SZ_CST + SZ_MU;
constexpr int    FILL_WORDS = (int)((SZ_HBUF + SZ_SP) / 4);

// ---------------- LDS ----------------
constexpr int SLAB_STRIDE = 264;                 // W staging rows (fp16)
constexpr int HL_STRIDE   = 1040;                // h rows (fp16), 2080 B
// post-staging: hl [8][1040] fp16 @0, swred[4][8][2] @16640, sredS[8][2] after
constexpr int SCAN_LDS    = 2 * 64 * SLAB_STRIDE * 2;  // 67584 (staging dominates)

__global__ void init_fill(unsigned* __restrict__ p, int n) {
    int i = blockIdx.x * blockDim.x + threadIdx.x;
    if (i < n) p[i] = 0xFFFFFFFFu;   // poison: tag never matches t=0/1 polls
}

__device__ __forceinline__ void split_bf16(float v, bf16_t& hi, bf16_t& lo) {
    hi = (bf16_t)v;
    lo = (bf16_t)(v - (float)hi);
}
__device__ __forceinline__ unsigned short f16_bits(f16_t f) {
    union { unsigned short u; f16_t f2; } x; x.f2 = f; return x.u;
}
__device__ __forceinline__ float tanh_fast(float x) {
    float e = __expf(2.f * x);
    return 1.f - 2.f * __builtin_amdgcn_rcpf(e + 1.f);
}
__device__ __forceinline__ void bar_lds() {
    asm volatile("s_waitcnt lgkmcnt(0)" ::: "memory");
    __builtin_amdgcn_s_barrier();
    asm volatile("" ::: "memory");
}

// ---------------- input-projection GEMM (split-precision bf16x2, r3-exact) -------
// MODE 0: A fp32 with series row-remap (layer0, K=256)
// MODE 1: A pre-split hi/lo bf16 (layer1, K=1024)
template<int KTOT, int MODE>
__global__ __launch_bounds__(256) void gemm_xp(
    const float*  __restrict__ Afp,
    const bf16_t* __restrict__ Ahi,
    const bf16_t* __restrict__ Alo,
    const float*  __restrict__ W,
    const float*  __restrict__ bias,
    float*        __restrict__ xp,
    int t0)
{
    __shared__ bf16_t Ash[64][40], Asl[64][40], Bsh[64][40], Bsl[64][40];
    const int bm = blockIdx.x / (ZDIM/64);
    const int bn = blockIdx.x % (ZDIM/64);
    const int tid  = threadIdx.x;
    const int lane = tid & 63;
    const int w    = tid >> 6;
    const int wm = w >> 1, wn = w & 1;
    const int q   = lane >> 4;
    const int l15 = lane & 15;

    f32x4 acc[2][2] = {};

    const int sm = tid & 63;
    const int sk = (tid >> 6) * 8;
    const int gr = t0*32 + bm*64 + sm;
    const float*  Arow  = nullptr;
    const bf16_t* Ahrow = nullptr;
    const bf16_t* Alrow = nullptr;
    if constexpr (MODE == 0) {
        int tt = gr >> 5, bb = gr & 31;
        Arow = Afp + ((size_t)bb * T_STEPS + tt) * 256;
    } else {
        Ahrow = Ahi + (size_t)gr * HDIM;
        Alrow = Alo + (size_t)gr * HDIM;
    }
    const int gcol = bn*64 + sm;

    for (int k0 = 0; k0 < KTOT; k0 += 32) {
        if constexpr (MODE == 0) {
            f32x4 a0 = *(const f32x4*)(Arow + k0 + sk);
            f32x4 a1 = *(const f32x4*)(Arow + k0 + sk + 4);
            #pragma unroll
            for (int j = 0; j < 4; ++j) {
                split_bf16(a0[j], Ash[sm][sk+j],   Asl[sm][sk+j]);
                split_bf16(a1[j], Ash[sm][sk+4+j], Asl[sm][sk+4+j]);
            }
        } else {
            *(bf16x8*)&Ash[sm][sk] = *(const bf16x8*)(Ahrow + k0 + sk);
            *(bf16x8*)&Asl[sm][sk] = *(const bf16x8*)(Alrow + k0 + sk);
        }
        #pragma unroll
        for (int j = 0; j < 8; ++j) {
            float wv = W[(size_t)(k0 + sk + j) * ZDIM + gcol];
            split_bf16(wv, Bsh[sm][sk+j], Bsl[sm][sk+j]);
        }
        __syncthreads();
        #pragma unroll
        for (int mt = 0; mt < 2; ++mt) {
            #pragma unroll
            for (int nt = 0; nt < 2; ++nt) {
                bf16x8 ah = *(const bf16x8*)&Ash[wm*32 + mt*16 + l15][q*8];
                bf16x8 al = *(const bf16x8*)&Asl[wm*32 + mt*16 + l15][q*8];
                bf16x8 bh = *(const bf16x8*)&Bsh[wn*32 + nt*16 + l15][q*8];
                bf16x8 bl = *(const bf16x8*)&Bsl[wn*32 + nt*16 + l15][q*8];
                acc[mt][nt] = __builtin_amdgcn_mfma_f32_16x16x32_bf16(ah, bh, acc[mt][nt], 0, 0, 0);
                acc[mt][nt] = __builtin_amdgcn_mfma_f32_16x16x32_bf16(al, bh, acc[mt][nt], 0, 0, 0);
                acc[mt][nt] = __builtin_amdgcn_mfma_f32_16x16x32_bf16(ah, bl, acc[mt][nt], 0, 0, 0);
            }
        }
        __syncthreads();
    }
    #pragma unroll
    for (int mt = 0; mt < 2; ++mt) {
        int row = bm*64 + wm*32 + mt*16 + q*4;
        #pragma unroll
        for (int nt = 0; nt < 2; ++nt) {
            int col = bn*64 + wn*32 + nt*16 + l15;
            float bia = bias[col];
            #pragma unroll
            for (int r = 0; r < 4; ++r)
                xp[(size_t)(row + r)*ZDIM + col] = acc[mt][nt][r] + bia;
        }
    }
}

// ---------------- persistent recurrent scan: 2-hop, fp16 h broadcast (r3-exact) --
// grid 256 x 256. group gid=blk>>6 owns batches 8*gid..+7; block lid=blk&63 owns
// h-cols H0=lid*16. W_rec in registers as fp16 hi + fp16 lo*2048 A-fragments
// (err 2^-24) -> 2 MFMA chains.
// Per step: MFMA(f16) -> gates -> hop1: block LN partials tagged (t&3 in 2 fp32
// mantissa LSBs) -> poll 64 blocks -> butterfly -> owner computes LN + exact h
// (writes hseq/hst/outlast from fp32) -> hop2: publish h~ as {h0,h1} fp16 pairs,
// 1 tag bit per fp16 LSB (h err <= 1 ulp ~ 2^-11) -> wave-row poll 16KB/block ->
// unpack straight into fp16 LDS. Re-poison between layers kills cross-layer tag
// aliasing; within a layer skew<=1 step so parity+2-bit tags are safe.
__global__ __launch_bounds__(256, 1) void scan_kernel(
    const float* __restrict__ Wh,      // [1024][4096] fp32 recurrent rows
    const float* __restrict__ xp,      // [cT*32][4096] fp32 x-proj (incl bias)
    const float* __restrict__ gamma,
    const float* __restrict__ beta,
    unsigned*    Hbuf,                 // [2][32][512] tagged fp16-pair h dwords
    unsigned*    Sp,                   // [2][4][8][128] tagged LN partials
    bf16_t*      __restrict__ hseq_hi, // [T*32][1024] or null (layer0)
    bf16_t*      __restrict__ hseq_lo,
    float*       __restrict__ outlast, // [32][1024] or null (layer1)
    bf16_t*      __restrict__ hst_hi,  // [32][1024] chunk-carry
    bf16_t*      __restrict__ hst_lo,
    float*       __restrict__ cstate,  // [32][1024]
    float*       __restrict__ mustate, // [32]
    int t0, int t1)
{
    extern __shared__ char smem[];
    f16_t* slab_hi = (f16_t*)smem;                        // W staging
    f16_t* slab_lo = (f16_t*)(smem + 64*SLAB_STRIDE*2);
    f16_t* hl      = (f16_t*)smem;                        // [8][1040] fp16 post-staging
    float* swred   = (float*)(smem + 8*HL_STRIDE*2);      // [4 waves][8 batch][2]
    float* sredS   = swred + 64;                          // [8 batch][2]

    const int gid = blockIdx.x >> 6;
    const int lid = blockIdx.x & 63;
    const int B0  = gid * 8;
    const int H0  = lid * 16;
    const int tid  = threadIdx.x;
    const int lane = tid & 63;
    const int w    = tid >> 6;
    const int q    = lane >> 4;
    const int l15  = lane & 15;

    // ---- stage recurrent W slice -> registers (fp16 hi + fp16 lo*2048)
    f16x8 wf_hi[32], wf_lo[32];
    {
        const int kw   = tid >> 6;
        const int strip= (tid >> 4) & 3;
        const int col  = tid & 15;
        const int gc2  = strip*1024 + H0 + col;
        const int rr_w = col*4 + strip;
        #pragma unroll
        for (int s = 0; s < 4; ++s) {
            for (int j = 0; j < 64; ++j) {
                int kk = j*4 + kw;
                float v = Wh[(size_t)(s*256 + kk)*ZDIM + gc2];
                f16_t hi = (f16_t)v;
                f16_t lo = (f16_t)((v - (float)hi) * 2048.f);
                slab_hi[rr_w*SLAB_STRIDE + kk] = hi;
                slab_lo[rr_w*SLAB_STRIDE + kk] = lo;
            }
            __syncthreads();
            #pragma unroll
            for (int kbl = 0; kbl < 8; ++kbl) {
                wf_hi[s*8+kbl] = *(const f16x8*)&slab_hi[(16*w + l15)*SLAB_STRIDE + kbl*32 + q*8];
                wf_lo[s*8+kbl] = *(const f16x8*)&slab_lo[(16*w + l15)*SLAB_STRIDE + kbl*32 + q*8];
            }
            __syncthreads();
        }
    }

    // owner identity (MFMA C map)
    const int  bidx  = l15;
    const bool valid = bidx < 8;
    const int  batch = B0 + bidx;
    const int  hcl   = 4*w + q;
    const int  hcg   = H0 + hcl;
    const size_t xpbase = (size_t)batch * ZDIM + (size_t)H0 + hcl;
    const int hrow  = (l15 < 8) ? l15 : 7;

    // hop2 reader identity: wave w + lane-half owns rows rr = 2w + half
    const int half   = lane >> 5;
    const int lane32 = lane & 31;
    const int rr     = 2*w + half;
    const int rbatch = B0 + rr;

    float g_own = 0.f, b_own = 0.f;
    if (valid) { g_own = gamma[hcg]; b_own = beta[hcg]; }

    float c = 0.f, mu_own = 0.f;
    if (t0 > 0) {
        if (valid) {
            c = cstate[(size_t)batch*HDIM + hcg];
            mu_own = mustate[batch];
        }
        const int cb = tid * 4;
        #pragma unroll
        for (int r = 0; r < 8; ++r) {
            bf16x4 vh = *(const bf16x4*)&hst_hi[(size_t)(B0+r)*HDIM + cb];
            bf16x4 vl = *(const bf16x4*)&hst_lo[(size_t)(B0+r)*HDIM + cb];
            #pragma unroll
            for (int e = 0; e < 4; ++e)
                hl[r*HL_STRIDE + cb + e] = (f16_t)((float)vh[e] + (float)vl[e]);
        }
    }
    __syncthreads();

    // preload xp for first step
    float xpv[4] = {0.f, 0.f, 0.f, 0.f};
    if (valid) {
        const float* xpt = xp + xpbase;
        #pragma unroll
        for (int r = 0; r < 4; ++r) xpv[r] = xpt[(size_t)r * 1024];
    }

    const bool is_l0 = (hseq_hi != nullptr);

    #pragma unroll 1
    for (int t = t0; t < t1; ++t) {
        f32x4 acc_hh = {0.f,0.f,0.f,0.f}, acc_lh = acc_hh;
        if (t > 0) {
            const f16_t* Bp = hl + (size_t)hrow * HL_STRIDE + q*8;
            #pragma unroll
            for (int kb = 0; kb < 32; ++kb) {
                f16x8 b = *(const f16x8*)(Bp + kb*32);
                acc_hh = __builtin_amdgcn_mfma_f32_16x16x32_f16(wf_hi[kb], b, acc_hh, 0, 0, 0);
                acc_lh = __builtin_amdgcn_mfma_f32_16x16x32_f16(wf_lo[kb], b, acc_lh, 0, 0, 0);
            }
        }
        float z[4];
        #pragma unroll
        for (int r = 0; r < 4; ++r)
            z[r] = (acc_hh[r] + acc_lh[r]*(1.f/2048.f)) + xpv[r];

        float zi = fminf(fmaxf(z[0], -6.f), 3.f);
        float zf = fminf(fmaxf(z[1], -6.f), 3.f);
        float ig = __expf(zi);
        float fg = __expf(zf);
        float cand = tanh_fast(z[2]);
        float sg = 1.f / (1.f + __expf(-z[3]));
        c = fg * c + ig * cand;

        const int par = t & 1;
        const unsigned tg = (unsigned)(t & 3);
        const unsigned tgpat = (unsigned)(t & 1) | (((unsigned)(t >> 1) & 1u) << 16);

        // ---- hop1: intra-block LN partials -> tagged publish
        float dm = valid ? (c - mu_own) : 0.f;
        float s1 = dm, s2 = dm*dm;
        s1 += __shfl_xor(s1, 16); s2 += __shfl_xor(s2, 16);
        s1 += __shfl_xor(s1, 32); s2 += __shfl_xor(s2, 32);
        if (lane < 8) { swred[(w*8+lane)*2] = s1; swred[(w*8+lane)*2+1] = s2; }
        bar_lds();   // B1: swred ready

        if (tid < 8) {
            float S1p = swred[tid*2]       + swred[(8+tid)*2]
                      + swred[(16+tid)*2]  + swred[(24+tid)*2];
            float S2p = swred[tid*2+1]     + swred[(8+tid)*2+1]
                      + swred[(16+tid)*2+1]+ swred[(24+tid)*2+1];
            u32x2 pk;
            pk[0] = (__float_as_uint(S1p) & ~3u) | tg;
            pk[1] = (__float_as_uint(S2p) & ~3u) | tg;
            *(volatile u32x2*)(Sp + (((size_t)par*4 + gid)*8 + tid)*128 + (size_t)lid*2) = pk;
        }

        // xp prefetch for t+1: flies through both polls
        if (valid && t+1 < t1) {
            const float* xpt = xp + (size_t)(t+1 - t0) * (BATCH*ZDIM) + xpbase;
            #pragma unroll
            for (int r = 0; r < 4; ++r) xpv[r] = xpt[(size_t)r * 1024];
        }

        // ---- poll partials (self-validating), 32-lane reduce per batch
        {
            const int prr = tid >> 5, jj = tid & 31;
            volatile const u32x4* spb =
                (volatile const u32x4*)(Sp + (((size_t)par*4 + gid)*8 + prr)*128 + (size_t)jj*4);
            u32x4 sv = *spb;
            while ((((sv[0]^tg)|(sv[1]^tg)|(sv[2]^tg)|(sv[3]^tg)) & 3u) != 0u) {
                __builtin_amdgcn_s_sleep(1);
                sv = *spb;
            }
            float s1p = __uint_as_float(sv[0] & ~3u) + __uint_as_float(sv[2] & ~3u);
            float s2p = __uint_as_float(sv[1] & ~3u) + __uint_as_float(sv[3] & ~3u);
            #pragma unroll
            for (int m = 1; m < 32; m <<= 1) {
                s1p += __shfl_xor(s1p, m);
                s2p += __shfl_xor(s2p, m);
            }
            if (jj == 0) { sredS[prr*2] = s1p; sredS[prr*2+1] = s2p; }
        }
        bar_lds();   // B2: sredS ready

        // ---- owner: LN + exact h; publish h~ fp16 pair (tag: 1 LSB per fp16)
        const bool carry = (t == t1-1) && (t1 < T_STEPS);
        unsigned hbs = 0;
        if (valid) {
            float S1 = sredS[bidx*2], S2 = sredS[bidx*2+1];
            float dmu = S1 * (1.f/1024.f);
            float mu  = mu_own + dmu;
            float var = S2 * (1.f/1024.f) - dmu*dmu;
            float rsig = rsqrtf(var + 1e-5f);
            mu_own = mu;
            float ln   = (c - mu) * rsig * g_own + b_own;
            float hval = sg * tanh_fast(ln);
            if (is_l0) {
                bf16_t hi, lo; split_bf16(hval, hi, lo);
                hseq_hi[((size_t)t*32 + batch)*HDIM + hcg] = hi;
                hseq_lo[((size_t)t*32 + batch)*HDIM + hcg] = lo;
            }
            if (carry) {
                bf16_t hi, lo; split_bf16(hval, hi, lo);
                hst_hi[(size_t)batch*HDIM + hcg] = hi;
                hst_lo[(size_t)batch*HDIM + hcg] = lo;
            }
            if (outlast && t == T_STEPS-1)
                outlast[(size_t)batch*HDIM + hcg] = hval;
            unsigned tb = (q & 1) ? ((unsigned)(t >> 1) & 1u) : ((unsigned)t & 1u);
            hbs = ((unsigned)f16_bits((f16_t)hval) & 0xFFFEu) | tb;
        }
        unsigned pb2 = __shfl_xor(hbs, 16);   // partner col's bits (q ^ 1)
        if (valid && !(q & 1)) {
            unsigned dw = hbs | (pb2 << 16);
            *(volatile unsigned*)(Hbuf + ((size_t)par*32 + batch)*512 + ((unsigned)hcg >> 1)) = dw;
        }

        // ---- hop2: wave-row poll of fp16 h pairs straight into LDS
        if (t + 1 < t1) {
            volatile const u32x4* hb4 =
                (volatile const u32x4*)(Hbuf + ((size_t)par*32 + rbatch)*512) + lane32;
            u32x4 pv[4];
            #pragma unroll
            for (int k = 0; k < 4; ++k) pv[k] = hb4[(size_t)k*32];
            for (;;) {
                bool bad = false;
                #pragma unroll
                for (int k = 0; k < 4; ++k) {
                    unsigned m = ((pv[k][0]^tgpat)|(pv[k][1]^tgpat)
                                 |(pv[k][2]^tgpat)|(pv[k][3]^tgpat)) & 0x00010001u;
                    if (m) { pv[k] = hb4[(size_t)k*32]; bad = true; }
                }
                if (!bad) break;
                __builtin_amdgcn_s_sleep(1);
            }
            #pragma unroll
            for (int k = 0; k < 4; ++k) {
                u32x4 vv = pv[k] & 0xFFFEFFFEu;   // clear tag bits -> valid fp16 pairs
                *(u32x4*)&hl[(size_t)rr*HL_STRIDE + (size_t)k*256 + (size_t)lane32*8] = vv;
            }
            bar_lds();   // B3: hl ready for next step's MFMA
        }
    }

    // chunk-carry state
    if (t1 < T_STEPS) {
        if (valid) cstate[(size_t)batch*HDIM + hcg] = c;
        if (lid == 0 && w == 0 && q == 0 && valid) mustate[batch] = mu_own;
    }
}

extern "C" void kernel_launch(void* const* d_in, const int* in_sizes, int n_in,
                              void* d_out, int out_size, void* d_ws, size_t ws_size,
                              hipStream_t stream) {
    (void)in_sizes; (void)n_in;
    const float* series = (const float*)d_in[0];
    const float* W0  = (const float*)d_in[1];
    const float* b0  = (const float*)d_in[2];
    const float* g0  = (const float*)d_in[3];
    const float* be0 = (const float*)d_in[4];
    const float* W1  = (const float*)d_in[5];
    const float* b1  = (const float*)d_in[6];
    const float* g1  = (const float*)d_in[7];
    const float* be1 = (const float*)d_in[8];
    float* out = (float*)d_out;
    unsigned char* ws = (unsigned char*)d_ws;

    int cT = 0;
    const int cands[4] = {256, 128, 64, 32};
    for (int i = 0; i < 4; ++i) {
        size_t need = (size_t)cands[i]*32*ZDIM*4 + 2*SZ_HSEQ + SZ_TAIL;
        if (need <= ws_size) { cT = cands[i]; break; }
    }
    if (cT == 0) {
        (void)hipMemsetAsync(d_out, 0, (size_t)out_size * sizeof(float), stream);
        return;
    }
    const size_t sz_xp = (size_t)cT*32*ZDIM*4;
    unsigned char* p = ws;
    float*    xp      = (float*)p;    p += sz_xp;
    bf16_t*   hseq_hi = (bf16_t*)p;   p += SZ_HSEQ;
    bf16_t*   hseq_lo = (bf16_t*)p;   p += SZ_HSEQ;
    unsigned* Hbuf    = (unsigned*)p; p += SZ_HBUF;   // Hbuf+Sp contiguous for init_fill
    unsigned* Sp      = (unsigned*)p; p += SZ_SP;
    bf16_t*   hst_hi  = (bf16_t*)p;   p += SZ_HST;
    bf16_t*   hst_lo  = (bf16_t*)p;   p += SZ_HST;
    float*    cstate  = (float*)p;    p += SZ_CST;
    float*    mustate = (float*)p;

    (void)hipFuncSetAttribute((const void*)scan_kernel,
                              hipFuncAttributeMaxDynamicSharedMemorySize, SCAN_LDS);

    const int nch = T_STEPS / cT;
    const int gemm_grid = (cT*32/64) * (ZDIM/64);

    // ---- layer 0 ----
    init_fill<<<(FILL_WORDS + 255)/256, 256, 0, stream>>>(Hbuf, FILL_WORDS);
    for (int ci = 0; ci < nch; ++ci) {
        int t0 = ci*cT, t1 = t0 + cT;
        gemm_xp<256, 0><<<gemm_grid, 256, 0, stream>>>(
            series, nullptr, nullptr, W0, b0, xp, t0);
        scan_kernel<<<256, 256, SCAN_LDS, stream>>>(
            W0 + (size_t)256*ZDIM, xp, g0, be0, Hbuf, Sp,
            hseq_hi, hseq_lo, nullptr, hst_hi, hst_lo, cstate, mustate, t0, t1);
    }
    // ---- layer 1 (re-poison kills cross-layer tag aliasing at t=2,3) ----
    init_fill<<<(FILL_WORDS + 255)/256, 256, 0, stream>>>(Hbuf, FILL_WORDS);
    for (int ci = 0; ci < nch; ++ci) {
        int t0 = ci*cT, t1 = t0 + cT;
        gemm_xp<1024, 1><<<gemm_grid, 256, 0, stream>>>(
            nullptr, hseq_hi, hseq_lo, W1, b1, xp, t0);
        scan_kernel<<<256, 256, SCAN_LDS, stream>>>(
            W1 + (size_t)1024*ZDIM, xp, g1, be1, Hbuf, Sp,
            nullptr, nullptr, out, hst_hi, hst_lo, cstate, mustate, t0, t1);
    }
}